// Round 10
// baseline (186.610 us; speedup 1.0000x reference)
//
#include <hip/hip_runtime.h>

#define HH 16
#define TT 4096
#define DD 64

typedef __attribute__((ext_vector_type(2))) __fp16 half2r;   // cvt_pkrtz result type
typedef __attribute__((ext_vector_type(4))) _Float16 half4;
typedef __attribute__((ext_vector_type(4))) float float4v;

// R7 structure (best: 91us): one block = 4 waves x 16 q rows = 64 q rows of
// one head; grid 1024 -> 4 blocks/CU, 4 independent barrier groups.
// Double-buffered 64-key K/V tiles, single barrier per tile.
// LDS swizzle (quarter-wave conflict-free, R6/R7-proven):
//   phys(row, o8) = row*128 + 16*((o8>>1)^(row&7)) + 8*((o8&1)^((row>>3)&1))
// R9 adds: exp2 domain (log2e folded into Q scale), packed cvt_pkrtz
// conversions, depth-2 prefetch via A/B register sets (no row clamps needed:
// cu_seqlens ends at T so tile rows never exceed T-1).
__global__ __launch_bounds__(256, 4) void pa_fwd(
    const float* __restrict__ qg, const float* __restrict__ kg,
    const float* __restrict__ vg, const int* __restrict__ cu,
    float* __restrict__ outg)
{
    __shared__ __align__(16) _Float16 Kl[2][64 * 64];
    __shared__ __align__(16) _Float16 Vl[2][64 * 64];

    const int tid  = threadIdx.x;
    const int lane = tid & 63;
    const int wave = tid >> 6;      // 0..3
    const int lr   = lane & 15;
    const int lg   = lane >> 4;

    // XCD swizzle: grid 1024 = 8 XCD x 128 contiguous work items
    const int bswz = ((int)blockIdx.x & 7) * 128 + ((int)blockIdx.x >> 3);
    const int h    = bswz >> 6;            // 0..15
    const int qblk = (bswz & 63) << 6;     // 64 q rows per block
    const int q    = qblk + wave * 16 + lr;

    // per-row segment bounds (searchsorted semantics)
    int s = 0;
    while (cu[s + 1] <= q) ++s;
    const int lo = cu[s], hi = cu[s + 1];

    // block-level staging range
    int sb = 0;
    while (cu[sb + 1] <= qblk) ++sb;
    const int blo = cu[sb];
    while (cu[sb + 1] <= qblk + 63) ++sb;
    const int bhi = cu[sb + 1];

    const int wlo = __shfl(lo, 0);    // wave min key
    const int whi = __shfl(hi, 15);   // wave max key
    const int mlo = __shfl(lo, 15);   // max lo over wave rows
    const int mhi = __shfl(hi, 0);    // min hi over wave rows

    // Q fragment (B operand), scaled by 1/sqrt(64) * log2(e)  [exp2 domain]
    const float qscale = 0.125f * 1.44269504088896f;
    const float* qrow = qg + ((size_t)h * TT + q) * DD;
    half4 qf[4];
#pragma unroll
    for (int ds = 0; ds < 4; ++ds) {
        float4v t4 = *(const float4v*)(qrow + ds * 16 + lg * 4);
        half2r a = __builtin_amdgcn_cvt_pkrtz(t4[0] * qscale, t4[1] * qscale);
        half2r b = __builtin_amdgcn_cvt_pkrtz(t4[2] * qscale, t4[3] * qscale);
        qf[ds][0] = (_Float16)a[0]; qf[ds][1] = (_Float16)a[1];
        qf[ds][2] = (_Float16)b[0]; qf[ds][3] = (_Float16)b[1];
    }

    const float* kh_ = kg + (size_t)h * TT * DD;
    const float* vh_ = vg + (size_t)h * TT * DD;

    // staging assignments
    const int srow = tid >> 2;          // K key row 0..63
    const int sch  = (tid & 3) << 4;    // K float chunk base (16 floats)
    const int vd   = tid & 63;          // Vt row (d column of V)

    // swizzled write offsets (bytes, loop-invariant)
    unsigned kwr[4], vwr[4];
#pragma unroll
    for (int i = 0; i < 4; ++i) {
        const int ko8 = (tid & 3) * 4 + i;
        kwr[i] = (unsigned)(srow * 128 + 16 * ((ko8 >> 1) ^ (srow & 7)) +
                            8 * ((ko8 & 1) ^ ((srow >> 3) & 1)));
        const int vo8 = wave * 4 + i;
        vwr[i] = (unsigned)(vd * 128 + 16 * ((vo8 >> 1) ^ (vd & 7)) +
                            8 * ((vo8 & 1) ^ ((vd >> 3) & 1)));
    }
    // swizzled fragment-read bases (bytes): rbase[x] + y*2048
    unsigned rbase[4];
#pragma unroll
    for (int i = 0; i < 4; ++i)
        rbase[i] = (unsigned)(lr * 128 + 16 * (((2 * i + (lg >> 1))) ^ (lr & 7)) +
                              8 * ((lg & 1) ^ ((lr >> 3) & 1)));

    // depth-2 prefetch register sets (tile rows never exceed T-1: no clamps)
    float4v kqA[4], kqB[4];
    float vvA[16], vvB[16];

#define ISSUE(KT, kq, vv)                                                      \
    {                                                                          \
        const float4v* kp = (const float4v*)(kh_ + (size_t)((KT) + srow) * DD + sch); \
        kq[0] = kp[0]; kq[1] = kp[1]; kq[2] = kp[2]; kq[3] = kp[3];            \
        const float* vp = vh_ + (size_t)((KT) + wave * 16) * DD + vd;          \
        _Pragma("unroll")                                                      \
        for (int c = 0; c < 16; ++c) vv[c] = vp[c * DD];                       \
    }

#define PACK(kq, vv, CUR)                                                      \
    {                                                                          \
        char* Kb = (char*)Kl[CUR];                                             \
        char* Vb = (char*)Vl[CUR];                                             \
        _Pragma("unroll")                                                      \
        for (int i = 0; i < 4; ++i) {                                          \
            half2r a = __builtin_amdgcn_cvt_pkrtz(kq[i][0], kq[i][1]);         \
            half2r b = __builtin_amdgcn_cvt_pkrtz(kq[i][2], kq[i][3]);         \
            half4 hk;                                                          \
            hk[0] = (_Float16)a[0]; hk[1] = (_Float16)a[1];                    \
            hk[2] = (_Float16)b[0]; hk[3] = (_Float16)b[1];                    \
            *(half4*)(Kb + kwr[i]) = hk;                                       \
        }                                                                      \
        _Pragma("unroll")                                                      \
        for (int i = 0; i < 4; ++i) {                                          \
            half2r a = __builtin_amdgcn_cvt_pkrtz(vv[4 * i], vv[4 * i + 1]);   \
            half2r b = __builtin_amdgcn_cvt_pkrtz(vv[4 * i + 2], vv[4 * i + 3]); \
            half4 hv;                                                          \
            hv[0] = (_Float16)a[0]; hv[1] = (_Float16)a[1];                    \
            hv[2] = (_Float16)b[0]; hv[3] = (_Float16)b[1];                    \
            *(half4*)(Vb + vwr[i]) = hv;                                       \
        }                                                                      \
    }

    const int t0k = blo & ~63;
    ISSUE(t0k, kqA, vvA);
    if (t0k + 64 < bhi) ISSUE(t0k + 64, kqB, vvB);

    float4v acc[4];
#pragma unroll
    for (int dt = 0; dt < 4; ++dt) acc[dt] = (float4v){0.f, 0.f, 0.f, 0.f};
    float m_run = -1e30f, lsum = 0.f;

    int cur = 0;
    for (int kt = t0k; kt < bhi; kt += 64) {
        // ---- pack + write LDS buf[cur]; reissue same reg set for t+2 ----
        if (cur == 0) { PACK(kqA, vvA, 0); } else { PACK(kqB, vvB, 1); }
        __syncthreads();   // the only barrier per tile
        if (kt + 128 < bhi) {
            if (cur == 0) { ISSUE(kt + 128, kqA, vvA); }
            else          { ISSUE(kt + 128, kqB, vvB); }
        }

        if (!(kt + 64 <= wlo || kt >= whi)) {
            const char* Kb = (const char*)Kl[cur];
            const char* Vb = (const char*)Vl[cur];

            // ---- QK^T (exp2 domain): St[key][q], 4 x 16-key quarters ----
            float st[4][4];
            const bool fullv = (kt >= mlo) && (kt + 64 <= mhi);  // wave-uniform
            __builtin_amdgcn_s_setprio(1);
#pragma unroll
            for (int t = 0; t < 4; ++t) {
                float4v sa = (float4v){0.f, 0.f, 0.f, 0.f};
#pragma unroll
                for (int ds = 0; ds < 4; ++ds) {
                    half4 kf = *(const half4*)(Kb + rbase[ds] + t * 2048);
                    sa = __builtin_amdgcn_mfma_f32_16x16x16f16(kf, qf[ds], sa, 0, 0, 0);
                }
                if (fullv) {
#pragma unroll
                    for (int j = 0; j < 4; ++j) st[t][j] = sa[j];
                } else {
#pragma unroll
                    for (int j = 0; j < 4; ++j) {
                        const int key = kt + t * 16 + lg * 4 + j;
                        st[t][j] = (key >= lo && key < hi) ? sa[j] : -1e30f;
                    }
                }
            }
            __builtin_amdgcn_s_setprio(0);

            // ---- online softmax in log2 units (per q row = lr) ----
            float tx = -1e30f;
#pragma unroll
            for (int t = 0; t < 4; ++t)
#pragma unroll
                for (int j = 0; j < 4; ++j) tx = fmaxf(tx, st[t][j]);
            tx = fmaxf(tx, __shfl_xor(tx, 16));
            tx = fmaxf(tx, __shfl_xor(tx, 32));

            // defer-max: rescale only when a row's max grew past m + 8*log2e
            if (__any(tx > m_run + 11.54f)) {
                const float mn = fmaxf(m_run, tx);
                const float a  = exp2f(m_run - mn);
                lsum *= a;
#pragma unroll
                for (int dt = 0; dt < 4; ++dt)
#pragma unroll
                    for (int j = 0; j < 4; ++j) acc[dt][j] *= a;
                m_run = mn;
            }
            // all-masked rows self-heal at the first real tile (a=0 wipes acc,l)

            half4 pb[4];
            float ps = 0.f;
#pragma unroll
            for (int t = 0; t < 4; ++t) {
                float e0 = exp2f(st[t][0] - m_run);
                float e1 = exp2f(st[t][1] - m_run);
                float e2 = exp2f(st[t][2] - m_run);
                float e3 = exp2f(st[t][3] - m_run);
                ps += (e0 + e1) + (e2 + e3);
                half2r a = __builtin_amdgcn_cvt_pkrtz(e0, e1);
                half2r b = __builtin_amdgcn_cvt_pkrtz(e2, e3);
                pb[t][0] = (_Float16)a[0]; pb[t][1] = (_Float16)a[1];
                pb[t][2] = (_Float16)b[0]; pb[t][3] = (_Float16)b[1];
            }
            ps += __shfl_xor(ps, 16);
            ps += __shfl_xor(ps, 32);
            lsum += ps;

            // ---- PV: Ot += V^T * P^T ----
            __builtin_amdgcn_s_setprio(1);
#pragma unroll
            for (int t = 0; t < 4; ++t)
#pragma unroll
                for (int dt = 0; dt < 4; ++dt) {
                    half4 vf = *(const half4*)(Vb + rbase[t] + dt * 2048);
                    acc[dt] = __builtin_amdgcn_mfma_f32_16x16x16f16(vf, pb[t], acc[dt], 0, 0, 0);
                }
            __builtin_amdgcn_s_setprio(0);
        }
        cur ^= 1;
    }

    const float inv = 1.0f / lsum;
    float* orow = outg + ((size_t)h * TT + q) * DD;
#pragma unroll
    for (int dt = 0; dt < 4; ++dt) {
        float4v o;
#pragma unroll
        for (int j = 0; j < 4; ++j) o[j] = acc[dt][j] * inv;
        *(float4v*)(orow + dt * 16 + lg * 4) = o;
    }
#undef ISSUE
#undef PACK
}

extern "C" void kernel_launch(void* const* d_in, const int* in_sizes, int n_in,
                              void* d_out, int out_size, void* d_ws, size_t ws_size,
                              hipStream_t stream) {
    const float* q  = (const float*)d_in[0];
    const float* k  = (const float*)d_in[1];
    const float* v  = (const float*)d_in[2];
    const int*   cu = (const int*)d_in[3];
    float* out = (float*)d_out;

    dim3 grid(HH * (TT / 64));   // 1024
    dim3 block(256);
    hipLaunchKernelGGL(pa_fwd, grid, block, 0, stream, q, k, v, cu, out);
}

// Round 11
// 90.514 us; speedup vs baseline: 2.0617x; 2.0617x over previous
//
#include <hip/hip_runtime.h>

#define HH 16
#define TT 4096
#define DD 64

typedef __attribute__((ext_vector_type(2))) __fp16 half2r;   // cvt_pkrtz result type
typedef __attribute__((ext_vector_type(4))) _Float16 half4;
typedef __attribute__((ext_vector_type(4))) float float4v;

// R7 structure (best: 91us): one block = 4 waves x 16 q rows = 64 q rows of
// one head; grid 1024 -> 4 blocks/CU, 4 independent barrier groups.
// Double-buffered 64-key K/V tiles, single barrier per tile, DEPTH-1 prefetch
// (depth-2 spilled to scratch in R10: WRITE_SIZE 16->218MB — reverted).
// LDS swizzle (quarter-wave conflict-free, R6/R7-proven):
//   phys(row, o8) = row*128 + 16*((o8>>1)^(row&7)) + 8*((o8&1)^((row>>3)&1))
// Kept from R9/R10: exp2 domain (log2e folded into Q scale), packed cvt_pkrtz.
__global__ __launch_bounds__(256, 4) void pa_fwd(
    const float* __restrict__ qg, const float* __restrict__ kg,
    const float* __restrict__ vg, const int* __restrict__ cu,
    float* __restrict__ outg)
{
    __shared__ __align__(16) _Float16 Kl[2][64 * 64];
    __shared__ __align__(16) _Float16 Vl[2][64 * 64];

    const int tid  = threadIdx.x;
    const int lane = tid & 63;
    const int wave = tid >> 6;      // 0..3
    const int lr   = lane & 15;
    const int lg   = lane >> 4;

    // XCD swizzle: grid 1024 = 8 XCD x 128 contiguous work items
    const int bswz = ((int)blockIdx.x & 7) * 128 + ((int)blockIdx.x >> 3);
    const int h    = bswz >> 6;            // 0..15
    const int qblk = (bswz & 63) << 6;     // 64 q rows per block
    const int q    = qblk + wave * 16 + lr;

    // per-row segment bounds (searchsorted semantics)
    int s = 0;
    while (cu[s + 1] <= q) ++s;
    const int lo = cu[s], hi = cu[s + 1];

    // block-level staging range
    int sb = 0;
    while (cu[sb + 1] <= qblk) ++sb;
    const int blo = cu[sb];
    while (cu[sb + 1] <= qblk + 63) ++sb;
    const int bhi = cu[sb + 1];

    const int wlo = __shfl(lo, 0);    // wave min key
    const int whi = __shfl(hi, 15);   // wave max key
    const int mlo = __shfl(lo, 15);   // max lo over wave rows
    const int mhi = __shfl(hi, 0);    // min hi over wave rows

    // Q fragment (B operand), scaled by 1/sqrt(64) * log2(e)  [exp2 domain]
    const float qscale = 0.125f * 1.44269504088896f;
    const float* qrow = qg + ((size_t)h * TT + q) * DD;
    half4 qf[4];
#pragma unroll
    for (int ds = 0; ds < 4; ++ds) {
        float4v t4 = *(const float4v*)(qrow + ds * 16 + lg * 4);
        half2r a = __builtin_amdgcn_cvt_pkrtz(t4[0] * qscale, t4[1] * qscale);
        half2r b = __builtin_amdgcn_cvt_pkrtz(t4[2] * qscale, t4[3] * qscale);
        qf[ds][0] = (_Float16)a[0]; qf[ds][1] = (_Float16)a[1];
        qf[ds][2] = (_Float16)b[0]; qf[ds][3] = (_Float16)b[1];
    }

    const float* kh_ = kg + (size_t)h * TT * DD;
    const float* vh_ = vg + (size_t)h * TT * DD;

    // staging assignments
    const int srow = tid >> 2;          // K key row 0..63
    const int sch  = (tid & 3) << 4;    // K float chunk base (16 floats)
    const int vd   = tid & 63;          // Vt row (d column of V)

    // swizzled write offsets (bytes, loop-invariant)
    unsigned kwr[4], vwr[4];
#pragma unroll
    for (int i = 0; i < 4; ++i) {
        const int ko8 = (tid & 3) * 4 + i;
        kwr[i] = (unsigned)(srow * 128 + 16 * ((ko8 >> 1) ^ (srow & 7)) +
                            8 * ((ko8 & 1) ^ ((srow >> 3) & 1)));
        const int vo8 = wave * 4 + i;
        vwr[i] = (unsigned)(vd * 128 + 16 * ((vo8 >> 1) ^ (vd & 7)) +
                            8 * ((vo8 & 1) ^ ((vd >> 3) & 1)));
    }
    // swizzled fragment-read bases (bytes): rbase[x] + y*2048
    unsigned rbase[4];
#pragma unroll
    for (int i = 0; i < 4; ++i)
        rbase[i] = (unsigned)(lr * 128 + 16 * (((2 * i + (lg >> 1))) ^ (lr & 7)) +
                              8 * ((lg & 1) ^ ((lr >> 3) & 1)));

    // depth-1 prefetch registers (tile rows never exceed T-1: cu ends at T)
    float4v kq[4];
    float vv[16];

#define ISSUE(KT)                                                              \
    {                                                                          \
        const float4v* kp = (const float4v*)(kh_ + (size_t)((KT) + srow) * DD + sch); \
        kq[0] = kp[0]; kq[1] = kp[1]; kq[2] = kp[2]; kq[3] = kp[3];            \
        const float* vp = vh_ + (size_t)((KT) + wave * 16) * DD + vd;          \
        _Pragma("unroll")                                                      \
        for (int c = 0; c < 16; ++c) vv[c] = vp[c * DD];                       \
    }

    const int t0k = blo & ~63;
    ISSUE(t0k);

    float4v acc[4];
#pragma unroll
    for (int dt = 0; dt < 4; ++dt) acc[dt] = (float4v){0.f, 0.f, 0.f, 0.f};
    float m_run = -1e30f, lsum = 0.f;

    int cur = 0;
    for (int kt = t0k; kt < bhi; kt += 64) {
        // ---- pack + write LDS buf[cur] ----
        {
            char* Kb = (char*)Kl[cur];
            char* Vb = (char*)Vl[cur];
#pragma unroll
            for (int i = 0; i < 4; ++i) {
                half2r a = __builtin_amdgcn_cvt_pkrtz(kq[i][0], kq[i][1]);
                half2r b = __builtin_amdgcn_cvt_pkrtz(kq[i][2], kq[i][3]);
                half4 hk;
                hk[0] = (_Float16)a[0]; hk[1] = (_Float16)a[1];
                hk[2] = (_Float16)b[0]; hk[3] = (_Float16)b[1];
                *(half4*)(Kb + kwr[i]) = hk;
            }
#pragma unroll
            for (int i = 0; i < 4; ++i) {
                half2r a = __builtin_amdgcn_cvt_pkrtz(vv[4 * i], vv[4 * i + 1]);
                half2r b = __builtin_amdgcn_cvt_pkrtz(vv[4 * i + 2], vv[4 * i + 3]);
                half4 hv;
                hv[0] = (_Float16)a[0]; hv[1] = (_Float16)a[1];
                hv[2] = (_Float16)b[0]; hv[3] = (_Float16)b[1];
                *(half4*)(Vb + vwr[i]) = hv;
            }
        }
        __syncthreads();   // the only barrier per tile

        if (kt + 64 < bhi) ISSUE(kt + 64);   // wave-uniform

        if (!(kt + 64 <= wlo || kt >= whi)) {
            const char* Kb = (const char*)Kl[cur];
            const char* Vb = (const char*)Vl[cur];

            // ---- QK^T (exp2 domain): St[key][q], 4 x 16-key quarters ----
            float st[4][4];
            const bool fullv = (kt >= mlo) && (kt + 64 <= mhi);  // wave-uniform
            __builtin_amdgcn_s_setprio(1);
#pragma unroll
            for (int t = 0; t < 4; ++t) {
                float4v sa = (float4v){0.f, 0.f, 0.f, 0.f};
#pragma unroll
                for (int ds = 0; ds < 4; ++ds) {
                    half4 kf = *(const half4*)(Kb + rbase[ds] + t * 2048);
                    sa = __builtin_amdgcn_mfma_f32_16x16x16f16(kf, qf[ds], sa, 0, 0, 0);
                }
                if (fullv) {
#pragma unroll
                    for (int j = 0; j < 4; ++j) st[t][j] = sa[j];
                } else {
#pragma unroll
                    for (int j = 0; j < 4; ++j) {
                        const int key = kt + t * 16 + lg * 4 + j;
                        st[t][j] = (key >= lo && key < hi) ? sa[j] : -1e30f;
                    }
                }
            }
            __builtin_amdgcn_s_setprio(0);

            // ---- online softmax in log2 units (per q row = lr) ----
            float tx = -1e30f;
#pragma unroll
            for (int t = 0; t < 4; ++t)
#pragma unroll
                for (int j = 0; j < 4; ++j) tx = fmaxf(tx, st[t][j]);
            tx = fmaxf(tx, __shfl_xor(tx, 16));
            tx = fmaxf(tx, __shfl_xor(tx, 32));

            // defer-max: rescale only when a row's max grew past m + 8*log2e
            if (__any(tx > m_run + 11.54f)) {
                const float mn = fmaxf(m_run, tx);
                const float a  = exp2f(m_run - mn);
                lsum *= a;
#pragma unroll
                for (int dt = 0; dt < 4; ++dt)
#pragma unroll
                    for (int j = 0; j < 4; ++j) acc[dt][j] *= a;
                m_run = mn;
            }
            // all-masked rows self-heal at the first real tile (a=0 wipes acc,l)

            half4 pb[4];
            float ps = 0.f;
#pragma unroll
            for (int t = 0; t < 4; ++t) {
                float e0 = exp2f(st[t][0] - m_run);
                float e1 = exp2f(st[t][1] - m_run);
                float e2 = exp2f(st[t][2] - m_run);
                float e3 = exp2f(st[t][3] - m_run);
                ps += (e0 + e1) + (e2 + e3);
                half2r a = __builtin_amdgcn_cvt_pkrtz(e0, e1);
                half2r b = __builtin_amdgcn_cvt_pkrtz(e2, e3);
                pb[t][0] = (_Float16)a[0]; pb[t][1] = (_Float16)a[1];
                pb[t][2] = (_Float16)b[0]; pb[t][3] = (_Float16)b[1];
            }
            ps += __shfl_xor(ps, 16);
            ps += __shfl_xor(ps, 32);
            lsum += ps;

            // ---- PV: Ot += V^T * P^T ----
            __builtin_amdgcn_s_setprio(1);
#pragma unroll
            for (int t = 0; t < 4; ++t)
#pragma unroll
                for (int dt = 0; dt < 4; ++dt) {
                    half4 vf = *(const half4*)(Vb + rbase[t] + dt * 2048);
                    acc[dt] = __builtin_amdgcn_mfma_f32_16x16x16f16(vf, pb[t], acc[dt], 0, 0, 0);
                }
            __builtin_amdgcn_s_setprio(0);
        }
        cur ^= 1;
    }

    const float inv = 1.0f / lsum;
    float* orow = outg + ((size_t)h * TT + q) * DD;
#pragma unroll
    for (int dt = 0; dt < 4; ++dt) {
        float4v o;
#pragma unroll
        for (int j = 0; j < 4; ++j) o[j] = acc[dt][j] * inv;
        *(float4v*)(orow + dt * 16 + lg * 4) = o;
    }
#undef ISSUE
}

extern "C" void kernel_launch(void* const* d_in, const int* in_sizes, int n_in,
                              void* d_out, int out_size, void* d_ws, size_t ws_size,
                              hipStream_t stream) {
    const float* q  = (const float*)d_in[0];
    const float* k  = (const float*)d_in[1];
    const float* v  = (const float*)d_in[2];
    const int*   cu = (const int*)d_in[3];
    float* out = (float*)d_out;

    dim3 grid(HH * (TT / 64));   // 1024
    dim3 block(256);
    hipLaunchKernelGGL(pa_fwd, grid, block, 0, stream, q, k, v, cu, out);
}

// Round 12
// 89.435 us; speedup vs baseline: 2.0865x; 1.0121x over previous
//
#include <hip/hip_runtime.h>

#define HH 16
#define TT 4096
#define DD 64

typedef __attribute__((ext_vector_type(2))) __fp16 half2r;   // cvt_pkrtz result
typedef __attribute__((ext_vector_type(4))) _Float16 half4;
typedef __attribute__((ext_vector_type(8))) _Float16 half8;
typedef __attribute__((ext_vector_type(2))) float float2v;
typedef __attribute__((ext_vector_type(4))) float float4v;

// R7/R11 structure: block = 4 waves x 16 q rows = 64 q rows of one head;
// grid 1024 -> 4 blocks/CU (4 independent barrier groups); dbuf 64-key
// K/V LDS tiles, single barrier/tile, depth-1 prefetch, exp2 domain,
// defer-max, setprio, XCD swizzle.
// R12: QK via mfma 16x16x32 (8 MFMA, 2-deep chains, b128 K frags);
// LDS = 16B-slot XOR swizzle only: phys16(row,s) = row*128 + ((s^(row&7))<<4)
// (b128 ops bank-balanced over the op; b64 reads 2-way = free per m136);
// all staging writes b128; V global loads as dwordx2; advancing pointers.
__global__ __launch_bounds__(256, 4) void pa_fwd(
    const float* __restrict__ qg, const float* __restrict__ kg,
    const float* __restrict__ vg, const int* __restrict__ cu,
    float* __restrict__ outg)
{
    __shared__ __align__(16) _Float16 Kl[2][64 * 64];   // [key][d]
    __shared__ __align__(16) _Float16 Vl[2][64 * 64];   // [d][key]

    const int tid  = threadIdx.x;
    const int lane = tid & 63;
    const int wave = tid >> 6;      // 0..3
    const int lr   = lane & 15;
    const int lg   = lane >> 4;

    // XCD swizzle: grid 1024 = 8 XCD x 128 contiguous work items
    const int bswz = ((int)blockIdx.x & 7) * 128 + ((int)blockIdx.x >> 3);
    const int h    = bswz >> 6;            // 0..15
    const int qblk = (bswz & 63) << 6;     // 64 q rows per block
    const int q    = qblk + wave * 16 + lr;

    // per-row segment bounds (searchsorted semantics)
    int s = 0;
    while (cu[s + 1] <= q) ++s;
    const int lo = cu[s], hi = cu[s + 1];

    // block-level staging range
    int sb = 0;
    while (cu[sb + 1] <= qblk) ++sb;
    const int blo = cu[sb];
    while (cu[sb + 1] <= qblk + 63) ++sb;
    const int bhi = cu[sb + 1];

    const int wlo = __shfl(lo, 0);    // wave min key
    const int whi = __shfl(hi, 15);   // wave max key
    const int mlo = __shfl(lo, 15);   // max lo over wave rows
    const int mhi = __shfl(hi, 0);    // min hi over wave rows

    // Q fragment for x32 QK (B operand): lane holds d = ds*32 + lg*8 + j
    const float qscale = 0.125f * 1.44269504088896f;   // 1/sqrt(64) * log2(e)
    const float* qrow = qg + ((size_t)h * TT + q) * DD;
    half8 qf8[2];
#pragma unroll
    for (int ds = 0; ds < 2; ++ds) {
        const float* qp = qrow + ds * 32 + lg * 8;
        float4v a = *(const float4v*)qp;
        float4v b = *(const float4v*)(qp + 4);
        half2r p0 = __builtin_amdgcn_cvt_pkrtz(a[0] * qscale, a[1] * qscale);
        half2r p1 = __builtin_amdgcn_cvt_pkrtz(a[2] * qscale, a[3] * qscale);
        half2r p2 = __builtin_amdgcn_cvt_pkrtz(b[0] * qscale, b[1] * qscale);
        half2r p3 = __builtin_amdgcn_cvt_pkrtz(b[2] * qscale, b[3] * qscale);
        qf8[ds][0] = (_Float16)p0[0]; qf8[ds][1] = (_Float16)p0[1];
        qf8[ds][2] = (_Float16)p1[0]; qf8[ds][3] = (_Float16)p1[1];
        qf8[ds][4] = (_Float16)p2[0]; qf8[ds][5] = (_Float16)p2[1];
        qf8[ds][6] = (_Float16)p3[0]; qf8[ds][7] = (_Float16)p3[1];
    }

    const float* kh_ = kg + (size_t)h * TT * DD;
    const float* vh_ = vg + (size_t)h * TT * DD;

    // ---- staging assignments ----
    // K: thread -> (row = tid>>2, 16-f32 chunk c = tid&3) -> slots 2c, 2c+1
    const int srow = tid >> 2;
    const int sc   = tid & 3;
    const unsigned kwrA = (unsigned)(srow * 128 + (((2 * sc)     ^ (srow & 7)) << 4));
    const unsigned kwrB = (unsigned)(srow * 128 + (((2 * sc + 1) ^ (srow & 7)) << 4));
    // V: thread -> (d-pair vd2 = tid&31 -> rows 2vd2, 2vd2+1; key octet vko = tid>>5)
    const int vd2 = tid & 31;
    const int vko = tid >> 5;
    const int vr0 = 2 * vd2, vr1 = 2 * vd2 + 1;
    const unsigned vwrA = (unsigned)(vr0 * 128 + ((vko ^ (vr0 & 7)) << 4));
    const unsigned vwrB = (unsigned)(vr1 * 128 + ((vko ^ (vr1 & 7)) << 4));

    // ---- fragment read bases ----
    // K (b128, x32): row = t*16+lr, slot = ds*4+lg
    const unsigned kb0 = (unsigned)(lr * 128 + (((lg)     ^ (lr & 7)) << 4));
    const unsigned kb1 = (unsigned)(lr * 128 + (((4 + lg) ^ (lr & 7)) << 4));
    // V (b64, x16 PV): row = dt*16+lr, o8 = t*4+lg -> slot 2t+(lg>>1), half lg&1
    unsigned vrb[4];
#pragma unroll
    for (int t = 0; t < 4; ++t)
        vrb[t] = (unsigned)(lr * 128 + (((2 * t + (lg >> 1)) ^ (lr & 7)) << 4) +
                            ((lg & 1) << 3));

    // depth-1 prefetch registers + advancing pointers
    float4v kq[4];
    float2v vv2[8];
    const int t0k = blo & ~63;
    const float4v* kp = (const float4v*)(kh_ + (size_t)(t0k + srow) * DD + sc * 16);
    const float*   vp = vh_ + (size_t)(t0k + vko * 8) * DD + vd2 * 2;

#define ISSUE()                                                                \
    {                                                                          \
        kq[0] = kp[0]; kq[1] = kp[1]; kq[2] = kp[2]; kq[3] = kp[3];            \
        kp += (64 * DD) / 4;                                                   \
        _Pragma("unroll")                                                      \
        for (int c = 0; c < 8; ++c) vv2[c] = *(const float2v*)(vp + c * DD);   \
        vp += 64 * DD;                                                         \
    }

    ISSUE();

    float4v acc[4];
#pragma unroll
    for (int dt = 0; dt < 4; ++dt) acc[dt] = (float4v){0.f, 0.f, 0.f, 0.f};
    float m_run = -1e30f, lsum = 0.f;

    int cur = 0;
    for (int kt = t0k; kt < bhi; kt += 64) {
        // ---- pack + write LDS buf[cur]: 4 b128 writes/thread ----
        {
            char* Kb = (char*)Kl[cur];
            char* Vb = (char*)Vl[cur];
            half8 hk0, hk1, hv0, hv1;
#pragma unroll
            for (int i = 0; i < 2; ++i) {
                half2r a = __builtin_amdgcn_cvt_pkrtz(kq[i][0], kq[i][1]);
                half2r b = __builtin_amdgcn_cvt_pkrtz(kq[i][2], kq[i][3]);
                hk0[4 * i + 0] = (_Float16)a[0]; hk0[4 * i + 1] = (_Float16)a[1];
                hk0[4 * i + 2] = (_Float16)b[0]; hk0[4 * i + 3] = (_Float16)b[1];
                half2r c2 = __builtin_amdgcn_cvt_pkrtz(kq[2 + i][0], kq[2 + i][1]);
                half2r d2 = __builtin_amdgcn_cvt_pkrtz(kq[2 + i][2], kq[2 + i][3]);
                hk1[4 * i + 0] = (_Float16)c2[0]; hk1[4 * i + 1] = (_Float16)c2[1];
                hk1[4 * i + 2] = (_Float16)d2[0]; hk1[4 * i + 3] = (_Float16)d2[1];
            }
#pragma unroll
            for (int i = 0; i < 4; ++i) {
                half2r a = __builtin_amdgcn_cvt_pkrtz(vv2[2 * i][0], vv2[2 * i + 1][0]);
                half2r b = __builtin_amdgcn_cvt_pkrtz(vv2[2 * i][1], vv2[2 * i + 1][1]);
                hv0[2 * i] = (_Float16)a[0]; hv0[2 * i + 1] = (_Float16)a[1];
                hv1[2 * i] = (_Float16)b[0]; hv1[2 * i + 1] = (_Float16)b[1];
            }
            *(half8*)(Kb + kwrA) = hk0;
            *(half8*)(Kb + kwrB) = hk1;
            *(half8*)(Vb + vwrA) = hv0;
            *(half8*)(Vb + vwrB) = hv1;
        }
        __syncthreads();   // the only barrier per tile

        if (kt + 64 < bhi) ISSUE();   // wave-uniform

        if (!(kt + 64 <= wlo || kt >= whi)) {
            const char* Kb = (const char*)Kl[cur];
            const char* Vb = (const char*)Vl[cur];

            // ---- QK^T via x32 MFMA: St[key][q], 4 x 16-key quarters ----
            float st[4][4];
            const bool fullv = (kt >= mlo) && (kt + 64 <= mhi);  // wave-uniform
            __builtin_amdgcn_s_setprio(1);
#pragma unroll
            for (int t = 0; t < 4; ++t) {
                float4v sa = (float4v){0.f, 0.f, 0.f, 0.f};
                half8 kf0 = *(const half8*)(Kb + kb0 + t * 2048);
                half8 kf1 = *(const half8*)(Kb + kb1 + t * 2048);
                sa = __builtin_amdgcn_mfma_f32_16x16x32_f16(kf0, qf8[0], sa, 0, 0, 0);
                sa = __builtin_amdgcn_mfma_f32_16x16x32_f16(kf1, qf8[1], sa, 0, 0, 0);
                if (fullv) {
#pragma unroll
                    for (int j = 0; j < 4; ++j) st[t][j] = sa[j];
                } else {
#pragma unroll
                    for (int j = 0; j < 4; ++j) {
                        const int key = kt + t * 16 + lg * 4 + j;
                        st[t][j] = (key >= lo && key < hi) ? sa[j] : -1e30f;
                    }
                }
            }
            __builtin_amdgcn_s_setprio(0);

            // ---- online softmax in log2 units (per q row = lr) ----
            float tx = fmaxf(fmaxf(st[0][0], st[0][1]), st[0][2]);
            tx = fmaxf(fmaxf(tx, st[0][3]), st[1][0]);
            tx = fmaxf(fmaxf(tx, st[1][1]), st[1][2]);
            tx = fmaxf(fmaxf(tx, st[1][3]), st[2][0]);
            tx = fmaxf(fmaxf(tx, st[2][1]), st[2][2]);
            tx = fmaxf(fmaxf(tx, st[2][3]), st[3][0]);
            tx = fmaxf(fmaxf(tx, st[3][1]), st[3][2]);
            tx = fmaxf(tx, st[3][3]);
            tx = fmaxf(tx, __shfl_xor(tx, 16));
            tx = fmaxf(tx, __shfl_xor(tx, 32));

            // defer-max: rescale only when a row's max grew past m + 8*log2e
            if (__any(tx > m_run + 11.54f)) {
                const float mn = fmaxf(m_run, tx);
                const float a  = exp2f(m_run - mn);
                lsum *= a;
#pragma unroll
                for (int dt = 0; dt < 4; ++dt)
#pragma unroll
                    for (int j = 0; j < 4; ++j) acc[dt][j] *= a;
                m_run = mn;
            }
            // all-masked rows self-heal at the first real tile (a=0 wipes acc,l)

            half4 pb[4];
            float ps = 0.f;
#pragma unroll
            for (int t = 0; t < 4; ++t) {
                float e0 = exp2f(st[t][0] - m_run);
                float e1 = exp2f(st[t][1] - m_run);
                float e2 = exp2f(st[t][2] - m_run);
                float e3 = exp2f(st[t][3] - m_run);
                ps += (e0 + e1) + (e2 + e3);
                half2r a = __builtin_amdgcn_cvt_pkrtz(e0, e1);
                half2r b = __builtin_amdgcn_cvt_pkrtz(e2, e3);
                pb[t][0] = (_Float16)a[0]; pb[t][1] = (_Float16)a[1];
                pb[t][2] = (_Float16)b[0]; pb[t][3] = (_Float16)b[1];
            }
            ps += __shfl_xor(ps, 16);
            ps += __shfl_xor(ps, 32);
            lsum += ps;

            // ---- PV (x16): Ot += V^T * P^T; P layout matches D of QK ----
            __builtin_amdgcn_s_setprio(1);
#pragma unroll
            for (int t = 0; t < 4; ++t)
#pragma unroll
                for (int dt = 0; dt < 4; ++dt) {
                    half4 vf = *(const half4*)(Vb + vrb[t] + dt * 2048);
                    acc[dt] = __builtin_amdgcn_mfma_f32_16x16x16f16(vf, pb[t], acc[dt], 0, 0, 0);
                }
            __builtin_amdgcn_s_setprio(0);
        }
        cur ^= 1;
    }

    const float inv = 1.0f / lsum;
    float* orow = outg + ((size_t)h * TT + q) * DD;
#pragma unroll
    for (int dt = 0; dt < 4; ++dt) {
        float4v o;
#pragma unroll
        for (int j = 0; j < 4; ++j) o[j] = acc[dt][j] * inv;
        *(float4v*)(orow + dt * 16 + lg * 4) = o;
    }
#undef ISSUE
}

extern "C" void kernel_launch(void* const* d_in, const int* in_sizes, int n_in,
                              void* d_out, int out_size, void* d_ws, size_t ws_size,
                              hipStream_t stream) {
    const float* q  = (const float*)d_in[0];
    const float* k  = (const float*)d_in[1];
    const float* v  = (const float*)d_in[2];
    const int*   cu = (const int*)d_in[3];
    float* out = (float*)d_out;

    dim3 grid(HH * (TT / 64));   // 1024
    dim3 block(256);
    hipLaunchKernelGGL(pa_fwd, grid, block, 0, stream, q, k, v, cu, out);
}

// Round 13
// 85.654 us; speedup vs baseline: 2.1787x; 1.0442x over previous
//
#include <hip/hip_runtime.h>

#define HH 16
#define TT 4096
#define DD 64

typedef __attribute__((ext_vector_type(2))) __fp16 half2r;   // cvt_pkrtz result
typedef __attribute__((ext_vector_type(4))) _Float16 half4;
typedef __attribute__((ext_vector_type(8))) _Float16 half8;
typedef __attribute__((ext_vector_type(2))) float float2v;
typedef __attribute__((ext_vector_type(4))) float float4v;

// R7/R11/R12 structure: block = 4 waves x 16 q rows = 64 q rows of one head;
// grid 1024 -> 4 blocks/CU (4 independent barrier groups); dbuf 64-key
// K/V LDS tiles, single barrier/tile, depth-1 prefetch, exp2 domain,
// setprio, XCD swizzle, x32 QK MFMA, 16B-slot XOR swizzle LDS.
// R13: kill per-tile cross-lane chain latency —
//  (a) lsum accumulated by MFMA with constant-ones A fragment (acc_l):
//      deletes the psum xor16/32 shuffles + adds from the VALU chain;
//  (b) defer-max check is per-lane only (15 fmax + __any); the 2 max
//      shuffles + rescale run only when triggered (rare after tile 1).
__global__ __launch_bounds__(256, 4) void pa_fwd(
    const float* __restrict__ qg, const float* __restrict__ kg,
    const float* __restrict__ vg, const int* __restrict__ cu,
    float* __restrict__ outg)
{
    __shared__ __align__(16) _Float16 Kl[2][64 * 64];   // [key][d]
    __shared__ __align__(16) _Float16 Vl[2][64 * 64];   // [d][key]

    const int tid  = threadIdx.x;
    const int lane = tid & 63;
    const int wave = tid >> 6;      // 0..3
    const int lr   = lane & 15;
    const int lg   = lane >> 4;

    // XCD swizzle: grid 1024 = 8 XCD x 128 contiguous work items
    const int bswz = ((int)blockIdx.x & 7) * 128 + ((int)blockIdx.x >> 3);
    const int h    = bswz >> 6;            // 0..15
    const int qblk = (bswz & 63) << 6;     // 64 q rows per block
    const int q    = qblk + wave * 16 + lr;

    // per-row segment bounds (searchsorted semantics)
    int s = 0;
    while (cu[s + 1] <= q) ++s;
    const int lo = cu[s], hi = cu[s + 1];

    // block-level staging range
    int sb = 0;
    while (cu[sb + 1] <= qblk) ++sb;
    const int blo = cu[sb];
    while (cu[sb + 1] <= qblk + 63) ++sb;
    const int bhi = cu[sb + 1];

    const int wlo = __shfl(lo, 0);    // wave min key
    const int whi = __shfl(hi, 15);   // wave max key
    const int mlo = __shfl(lo, 15);   // max lo over wave rows
    const int mhi = __shfl(hi, 0);    // min hi over wave rows

    // Q fragment for x32 QK (B operand): lane holds d = ds*32 + lg*8 + j
    const float qscale = 0.125f * 1.44269504088896f;   // 1/sqrt(64) * log2(e)
    const float* qrow = qg + ((size_t)h * TT + q) * DD;
    half8 qf8[2];
#pragma unroll
    for (int ds = 0; ds < 2; ++ds) {
        const float* qp = qrow + ds * 32 + lg * 8;
        float4v a = *(const float4v*)qp;
        float4v b = *(const float4v*)(qp + 4);
        half2r p0 = __builtin_amdgcn_cvt_pkrtz(a[0] * qscale, a[1] * qscale);
        half2r p1 = __builtin_amdgcn_cvt_pkrtz(a[2] * qscale, a[3] * qscale);
        half2r p2 = __builtin_amdgcn_cvt_pkrtz(b[0] * qscale, b[1] * qscale);
        half2r p3 = __builtin_amdgcn_cvt_pkrtz(b[2] * qscale, b[3] * qscale);
        qf8[ds][0] = (_Float16)p0[0]; qf8[ds][1] = (_Float16)p0[1];
        qf8[ds][2] = (_Float16)p1[0]; qf8[ds][3] = (_Float16)p1[1];
        qf8[ds][4] = (_Float16)p2[0]; qf8[ds][5] = (_Float16)p2[1];
        qf8[ds][6] = (_Float16)p3[0]; qf8[ds][7] = (_Float16)p3[1];
    }

    const float* kh_ = kg + (size_t)h * TT * DD;
    const float* vh_ = vg + (size_t)h * TT * DD;

    // ---- staging assignments ----
    const int srow = tid >> 2;
    const int sc   = tid & 3;
    const unsigned kwrA = (unsigned)(srow * 128 + (((2 * sc)     ^ (srow & 7)) << 4));
    const unsigned kwrB = (unsigned)(srow * 128 + (((2 * sc + 1) ^ (srow & 7)) << 4));
    const int vd2 = tid & 31;
    const int vko = tid >> 5;
    const int vr0 = 2 * vd2, vr1 = 2 * vd2 + 1;
    const unsigned vwrA = (unsigned)(vr0 * 128 + ((vko ^ (vr0 & 7)) << 4));
    const unsigned vwrB = (unsigned)(vr1 * 128 + ((vko ^ (vr1 & 7)) << 4));

    // ---- fragment read bases ----
    const unsigned kb0 = (unsigned)(lr * 128 + (((lg)     ^ (lr & 7)) << 4));
    const unsigned kb1 = (unsigned)(lr * 128 + (((4 + lg) ^ (lr & 7)) << 4));
    unsigned vrb[4];
#pragma unroll
    for (int t = 0; t < 4; ++t)
        vrb[t] = (unsigned)(lr * 128 + (((2 * t + (lg >> 1)) ^ (lr & 7)) << 4) +
                            ((lg & 1) << 3));

    // constant ones A-fragment for the lsum MFMA
    half4 onesv;
    onesv[0] = onesv[1] = onesv[2] = onesv[3] = (_Float16)1.0f;

    // depth-1 prefetch registers + advancing pointers
    float4v kq[4];
    float2v vv2[8];
    const int t0k = blo & ~63;
    const float4v* kp = (const float4v*)(kh_ + (size_t)(t0k + srow) * DD + sc * 16);
    const float*   vp = vh_ + (size_t)(t0k + vko * 8) * DD + vd2 * 2;

#define ISSUE()                                                                \
    {                                                                          \
        kq[0] = kp[0]; kq[1] = kp[1]; kq[2] = kp[2]; kq[3] = kp[3];            \
        kp += (64 * DD) / 4;                                                   \
        _Pragma("unroll")                                                      \
        for (int c = 0; c < 8; ++c) vv2[c] = *(const float2v*)(vp + c * DD);   \
        vp += 64 * DD;                                                         \
    }

    ISSUE();

    float4v acc[4];
#pragma unroll
    for (int dt = 0; dt < 4; ++dt) acc[dt] = (float4v){0.f, 0.f, 0.f, 0.f};
    float4v acc_l = (float4v){0.f, 0.f, 0.f, 0.f};   // lsum via ones-MFMA
    float m_run = -1e30f;

    int cur = 0;
    for (int kt = t0k; kt < bhi; kt += 64) {
        // ---- pack + write LDS buf[cur]: 4 b128 writes/thread ----
        {
            char* Kb = (char*)Kl[cur];
            char* Vb = (char*)Vl[cur];
            half8 hk0, hk1, hv0, hv1;
#pragma unroll
            for (int i = 0; i < 2; ++i) {
                half2r a = __builtin_amdgcn_cvt_pkrtz(kq[i][0], kq[i][1]);
                half2r b = __builtin_amdgcn_cvt_pkrtz(kq[i][2], kq[i][3]);
                hk0[4 * i + 0] = (_Float16)a[0]; hk0[4 * i + 1] = (_Float16)a[1];
                hk0[4 * i + 2] = (_Float16)b[0]; hk0[4 * i + 3] = (_Float16)b[1];
                half2r c2 = __builtin_amdgcn_cvt_pkrtz(kq[2 + i][0], kq[2 + i][1]);
                half2r d2 = __builtin_amdgcn_cvt_pkrtz(kq[2 + i][2], kq[2 + i][3]);
                hk1[4 * i + 0] = (_Float16)c2[0]; hk1[4 * i + 1] = (_Float16)c2[1];
                hk1[4 * i + 2] = (_Float16)d2[0]; hk1[4 * i + 3] = (_Float16)d2[1];
            }
#pragma unroll
            for (int i = 0; i < 4; ++i) {
                half2r a = __builtin_amdgcn_cvt_pkrtz(vv2[2 * i][0], vv2[2 * i + 1][0]);
                half2r b = __builtin_amdgcn_cvt_pkrtz(vv2[2 * i][1], vv2[2 * i + 1][1]);
                hv0[2 * i] = (_Float16)a[0]; hv0[2 * i + 1] = (_Float16)a[1];
                hv1[2 * i] = (_Float16)b[0]; hv1[2 * i + 1] = (_Float16)b[1];
            }
            *(half8*)(Kb + kwrA) = hk0;
            *(half8*)(Kb + kwrB) = hk1;
            *(half8*)(Vb + vwrA) = hv0;
            *(half8*)(Vb + vwrB) = hv1;
        }
        __syncthreads();   // the only barrier per tile

        if (kt + 64 < bhi) ISSUE();   // wave-uniform

        if (!(kt + 64 <= wlo || kt >= whi)) {
            const char* Kb = (const char*)Kl[cur];
            const char* Vb = (const char*)Vl[cur];

            // ---- QK^T via x32 MFMA: St[key][q], 4 x 16-key quarters ----
            float st[4][4];
            const bool fullv = (kt >= mlo) && (kt + 64 <= mhi);  // wave-uniform
            __builtin_amdgcn_s_setprio(1);
#pragma unroll
            for (int t = 0; t < 4; ++t) {
                float4v sa = (float4v){0.f, 0.f, 0.f, 0.f};
                half8 kf0 = *(const half8*)(Kb + kb0 + t * 2048);
                half8 kf1 = *(const half8*)(Kb + kb1 + t * 2048);
                sa = __builtin_amdgcn_mfma_f32_16x16x32_f16(kf0, qf8[0], sa, 0, 0, 0);
                sa = __builtin_amdgcn_mfma_f32_16x16x32_f16(kf1, qf8[1], sa, 0, 0, 0);
                if (fullv) {
#pragma unroll
                    for (int j = 0; j < 4; ++j) st[t][j] = sa[j];
                } else {
#pragma unroll
                    for (int j = 0; j < 4; ++j) {
                        const int key = kt + t * 16 + lg * 4 + j;
                        st[t][j] = (key >= lo && key < hi) ? sa[j] : -1e30f;
                    }
                }
            }
            __builtin_amdgcn_s_setprio(0);

            // ---- per-lane max only (no cross-lane in common path) ----
            float lmax = fmaxf(fmaxf(st[0][0], st[0][1]), fmaxf(st[0][2], st[0][3]));
            lmax = fmaxf(lmax, fmaxf(fmaxf(st[1][0], st[1][1]), fmaxf(st[1][2], st[1][3])));
            lmax = fmaxf(lmax, fmaxf(fmaxf(st[2][0], st[2][1]), fmaxf(st[2][2], st[2][3])));
            lmax = fmaxf(lmax, fmaxf(fmaxf(st[3][0], st[3][1]), fmaxf(st[3][2], st[3][3])));

            // defer-max: shuffles + rescale only when some lane exceeds m+8*log2e
            if (__any(lmax > m_run + 11.54f)) {
                float tx = fmaxf(lmax, __shfl_xor(lmax, 16));
                tx = fmaxf(tx, __shfl_xor(tx, 32));
                const float mn = fmaxf(m_run, tx);
                const float a  = exp2f(m_run - mn);
#pragma unroll
                for (int dt = 0; dt < 4; ++dt)
#pragma unroll
                    for (int j = 0; j < 4; ++j) acc[dt][j] *= a;
#pragma unroll
                for (int j = 0; j < 4; ++j) acc_l[j] *= a;
                m_run = mn;
            }
            // all-masked rows self-heal at their first real tile (a=0 wipes accs)

            half4 pb[4];
#pragma unroll
            for (int t = 0; t < 4; ++t) {
                float e0 = exp2f(st[t][0] - m_run);
                float e1 = exp2f(st[t][1] - m_run);
                float e2 = exp2f(st[t][2] - m_run);
                float e3 = exp2f(st[t][3] - m_run);
                half2r a = __builtin_amdgcn_cvt_pkrtz(e0, e1);
                half2r b = __builtin_amdgcn_cvt_pkrtz(e2, e3);
                pb[t][0] = (_Float16)a[0]; pb[t][1] = (_Float16)a[1];
                pb[t][2] = (_Float16)b[0]; pb[t][3] = (_Float16)b[1];
            }

            // ---- PV + lsum: Ot += V^T P^T; acc_l += ones * P^T ----
            __builtin_amdgcn_s_setprio(1);
#pragma unroll
            for (int t = 0; t < 4; ++t) {
#pragma unroll
                for (int dt = 0; dt < 4; ++dt) {
                    half4 vf = *(const half4*)(Vb + vrb[t] + dt * 2048);
                    acc[dt] = __builtin_amdgcn_mfma_f32_16x16x16f16(vf, pb[t], acc[dt], 0, 0, 0);
                }
                acc_l = __builtin_amdgcn_mfma_f32_16x16x16f16(onesv, pb[t], acc_l, 0, 0, 0);
            }
            __builtin_amdgcn_s_setprio(0);
        }
        cur ^= 1;
    }

    const float inv = 1.0f / acc_l[0];   // all acc_l rows equal lsum[q=lr]
    float* orow = outg + ((size_t)h * TT + q) * DD;
#pragma unroll
    for (int dt = 0; dt < 4; ++dt) {
        float4v o;
#pragma unroll
        for (int j = 0; j < 4; ++j) o[j] = acc[dt][j] * inv;
        *(float4v*)(orow + dt * 16 + lg * 4) = o;
    }
#undef ISSUE
}

extern "C" void kernel_launch(void* const* d_in, const int* in_sizes, int n_in,
                              void* d_out, int out_size, void* d_ws, size_t ws_size,
                              hipStream_t stream) {
    const float* q  = (const float*)d_in[0];
    const float* k  = (const float*)d_in[1];
    const float* v  = (const float*)d_in[2];
    const int*   cu = (const int*)d_in[3];
    float* out = (float*)d_out;

    dim3 grid(HH * (TT / 64));   // 1024
    dim3 block(256);
    hipLaunchKernelGGL(pa_fwd, grid, block, 0, stream, q, k, v, cu, out);
}

// Round 14
// 81.307 us; speedup vs baseline: 2.2951x; 1.0535x over previous
//
#include <hip/hip_runtime.h>

#define HH 16
#define TT 4096
#define DD 64

typedef __attribute__((ext_vector_type(2))) __fp16 half2r;   // cvt_pkrtz result
typedef __attribute__((ext_vector_type(4))) _Float16 half4;
typedef __attribute__((ext_vector_type(8))) _Float16 half8;
typedef __attribute__((ext_vector_type(4))) float float4v;

// Structure (R7..R13): block = 4 waves x 16 q rows = 64 q rows of one head;
// grid 1024 -> 4 blocks/CU; dbuf 64-key K/V LDS tiles, single barrier/tile,
// depth-1 prefetch, exp2 domain, defer-max (lazy shuffles), lsum via
// ones-MFMA, setprio, XCD swizzle, x32 QK MFMA.
// R14: (a) V staging conflict-free: thread owns d-rows {vd2, vd2+32} and
// writes 4 x ds_write_b64 under two-level swizzle
//   phys(row,u) = row*128 + 16*((u>>1)^(row&7)) + 8*((u&1)^((row>>3)&1));
// (b) V fragment reads for t=0,1 hoisted between QK and softmax.
__global__ __launch_bounds__(256, 4) void pa_fwd(
    const float* __restrict__ qg, const float* __restrict__ kg,
    const float* __restrict__ vg, const int* __restrict__ cu,
    float* __restrict__ outg)
{
    __shared__ __align__(16) _Float16 Kl[2][64 * 64];   // [key][d]
    __shared__ __align__(16) _Float16 Vl[2][64 * 64];   // [d][key]

    const int tid  = threadIdx.x;
    const int lane = tid & 63;
    const int wave = tid >> 6;      // 0..3
    const int lr   = lane & 15;
    const int lg   = lane >> 4;

    // XCD swizzle: grid 1024 = 8 XCD x 128 contiguous work items
    const int bswz = ((int)blockIdx.x & 7) * 128 + ((int)blockIdx.x >> 3);
    const int h    = bswz >> 6;            // 0..15
    const int qblk = (bswz & 63) << 6;     // 64 q rows per block
    const int q    = qblk + wave * 16 + lr;

    // per-row segment bounds (searchsorted semantics)
    int s = 0;
    while (cu[s + 1] <= q) ++s;
    const int lo = cu[s], hi = cu[s + 1];

    // block-level staging range
    int sb = 0;
    while (cu[sb + 1] <= qblk) ++sb;
    const int blo = cu[sb];
    while (cu[sb + 1] <= qblk + 63) ++sb;
    const int bhi = cu[sb + 1];

    const int wlo = __shfl(lo, 0);    // wave min key
    const int whi = __shfl(hi, 15);   // wave max key
    const int mlo = __shfl(lo, 15);   // max lo over wave rows
    const int mhi = __shfl(hi, 0);    // min hi over wave rows

    // Q fragment for x32 QK (B operand): lane holds d = ds*32 + lg*8 + j
    const float qscale = 0.125f * 1.44269504088896f;   // 1/sqrt(64) * log2(e)
    const float* qrow = qg + ((size_t)h * TT + q) * DD;
    half8 qf8[2];
#pragma unroll
    for (int ds = 0; ds < 2; ++ds) {
        const float* qp = qrow + ds * 32 + lg * 8;
        float4v a = *(const float4v*)qp;
        float4v b = *(const float4v*)(qp + 4);
        half2r p0 = __builtin_amdgcn_cvt_pkrtz(a[0] * qscale, a[1] * qscale);
        half2r p1 = __builtin_amdgcn_cvt_pkrtz(a[2] * qscale, a[3] * qscale);
        half2r p2 = __builtin_amdgcn_cvt_pkrtz(b[0] * qscale, b[1] * qscale);
        half2r p3 = __builtin_amdgcn_cvt_pkrtz(b[2] * qscale, b[3] * qscale);
        qf8[ds][0] = (_Float16)p0[0]; qf8[ds][1] = (_Float16)p0[1];
        qf8[ds][2] = (_Float16)p1[0]; qf8[ds][3] = (_Float16)p1[1];
        qf8[ds][4] = (_Float16)p2[0]; qf8[ds][5] = (_Float16)p2[1];
        qf8[ds][6] = (_Float16)p3[0]; qf8[ds][7] = (_Float16)p3[1];
    }

    const float* kh_ = kg + (size_t)h * TT * DD;
    const float* vh_ = vg + (size_t)h * TT * DD;

    // ---- staging assignments ----
    // K: thread -> (row = tid>>2, 16-f32 chunk sc = tid&3) -> slots 2sc, 2sc+1
    const int srow = tid >> 2;
    const int sc   = tid & 3;
    const unsigned kwrA = (unsigned)(srow * 128 + (((2 * sc)     ^ (srow & 7)) << 4));
    const unsigned kwrB = (unsigned)(srow * 128 + (((2 * sc + 1) ^ (srow & 7)) << 4));
    // V: thread -> d-rows {vd2, vd2+32}, key octet vko (keys 8vko..8vko+7)
    const int vd2 = tid & 31;
    const int vko = tid >> 5;
    const int vslot = vko ^ (vd2 & 7);
    const int vhb   = (vd2 >> 3) & 1;
    const unsigned vwA0 = (unsigned)(vd2 * 128 + vslot * 16 + 8 * vhb);        // u=2vko
    const unsigned vwA1 = (unsigned)(vd2 * 128 + vslot * 16 + 8 * (1 ^ vhb)); // u=2vko+1
    const unsigned vwB0 = vwA0 + 32 * 128;
    const unsigned vwB1 = vwA1 + 32 * 128;

    // ---- fragment read bases ----
    const unsigned kb0 = (unsigned)(lr * 128 + (((lg)     ^ (lr & 7)) << 4));
    const unsigned kb1 = (unsigned)(lr * 128 + (((4 + lg) ^ (lr & 7)) << 4));
    unsigned vrb[4];
#pragma unroll
    for (int t = 0; t < 4; ++t)
        vrb[t] = (unsigned)(lr * 128 + (((2 * t + (lg >> 1)) ^ (lr & 7)) << 4) +
                            (((lg & 1) ^ ((lr >> 3) & 1)) << 3));

    // constant ones A-fragment for the lsum MFMA
    half4 onesv;
    onesv[0] = onesv[1] = onesv[2] = onesv[3] = (_Float16)1.0f;

    // depth-1 prefetch registers + advancing pointers
    float4v kq[4];
    float vvA[8], vvB[8];
    const int t0k = blo & ~63;
    const float4v* kp = (const float4v*)(kh_ + (size_t)(t0k + srow) * DD + sc * 16);
    const float*   vp = vh_ + (size_t)(t0k + vko * 8) * DD + vd2;

#define ISSUE()                                                                \
    {                                                                          \
        kq[0] = kp[0]; kq[1] = kp[1]; kq[2] = kp[2]; kq[3] = kp[3];            \
        kp += (64 * DD) / 4;                                                   \
        _Pragma("unroll")                                                      \
        for (int c = 0; c < 8; ++c) {                                          \
            vvA[c] = vp[c * DD];                                               \
            vvB[c] = vp[c * DD + 32];                                          \
        }                                                                      \
        vp += 64 * DD;                                                         \
    }

    ISSUE();

    float4v acc[4];
#pragma unroll
    for (int dt = 0; dt < 4; ++dt) acc[dt] = (float4v){0.f, 0.f, 0.f, 0.f};
    float4v acc_l = (float4v){0.f, 0.f, 0.f, 0.f};   // lsum via ones-MFMA
    float m_run = -1e30f;

    int cur = 0;
    for (int kt = t0k; kt < bhi; kt += 64) {
        // ---- pack + write LDS buf[cur] ----
        {
            char* Kb = (char*)Kl[cur];
            char* Vb = (char*)Vl[cur];
            half8 hk0, hk1;
#pragma unroll
            for (int i = 0; i < 2; ++i) {
                half2r a = __builtin_amdgcn_cvt_pkrtz(kq[i][0], kq[i][1]);
                half2r b = __builtin_amdgcn_cvt_pkrtz(kq[i][2], kq[i][3]);
                hk0[4 * i + 0] = (_Float16)a[0]; hk0[4 * i + 1] = (_Float16)a[1];
                hk0[4 * i + 2] = (_Float16)b[0]; hk0[4 * i + 3] = (_Float16)b[1];
                half2r c2 = __builtin_amdgcn_cvt_pkrtz(kq[2 + i][0], kq[2 + i][1]);
                half2r d2 = __builtin_amdgcn_cvt_pkrtz(kq[2 + i][2], kq[2 + i][3]);
                hk1[4 * i + 0] = (_Float16)c2[0]; hk1[4 * i + 1] = (_Float16)c2[1];
                hk1[4 * i + 2] = (_Float16)d2[0]; hk1[4 * i + 3] = (_Float16)d2[1];
            }
            *(half8*)(Kb + kwrA) = hk0;
            *(half8*)(Kb + kwrB) = hk1;

            half4 uA0, uA1, uB0, uB1;
            {
                half2r a = __builtin_amdgcn_cvt_pkrtz(vvA[0], vvA[1]);
                half2r b = __builtin_amdgcn_cvt_pkrtz(vvA[2], vvA[3]);
                uA0[0] = (_Float16)a[0]; uA0[1] = (_Float16)a[1];
                uA0[2] = (_Float16)b[0]; uA0[3] = (_Float16)b[1];
                half2r c2 = __builtin_amdgcn_cvt_pkrtz(vvA[4], vvA[5]);
                half2r d2 = __builtin_amdgcn_cvt_pkrtz(vvA[6], vvA[7]);
                uA1[0] = (_Float16)c2[0]; uA1[1] = (_Float16)c2[1];
                uA1[2] = (_Float16)d2[0]; uA1[3] = (_Float16)d2[1];
                half2r e = __builtin_amdgcn_cvt_pkrtz(vvB[0], vvB[1]);
                half2r f = __builtin_amdgcn_cvt_pkrtz(vvB[2], vvB[3]);
                uB0[0] = (_Float16)e[0]; uB0[1] = (_Float16)e[1];
                uB0[2] = (_Float16)f[0]; uB0[3] = (_Float16)f[1];
                half2r g = __builtin_amdgcn_cvt_pkrtz(vvB[4], vvB[5]);
                half2r k2 = __builtin_amdgcn_cvt_pkrtz(vvB[6], vvB[7]);
                uB1[0] = (_Float16)g[0]; uB1[1] = (_Float16)g[1];
                uB1[2] = (_Float16)k2[0]; uB1[3] = (_Float16)k2[1];
            }
            *(half4*)(Vb + vwA0) = uA0;
            *(half4*)(Vb + vwA1) = uA1;
            *(half4*)(Vb + vwB0) = uB0;
            *(half4*)(Vb + vwB1) = uB1;
        }
        __syncthreads();   // the only barrier per tile

        if (kt + 64 < bhi) ISSUE();   // wave-uniform

        if (!(kt + 64 <= wlo || kt >= whi)) {
            const char* Kb = (const char*)Kl[cur];
            const char* Vb = (const char*)Vl[cur];

            // ---- QK^T via x32 MFMA: St[key][q], 4 x 16-key quarters ----
            float st[4][4];
            const bool fullv = (kt >= mlo) && (kt + 64 <= mhi);  // wave-uniform
            __builtin_amdgcn_s_setprio(1);
#pragma unroll
            for (int t = 0; t < 4; ++t) {
                float4v sa = (float4v){0.f, 0.f, 0.f, 0.f};
                half8 kf0 = *(const half8*)(Kb + kb0 + t * 2048);
                half8 kf1 = *(const half8*)(Kb + kb1 + t * 2048);
                sa = __builtin_amdgcn_mfma_f32_16x16x32_f16(kf0, qf8[0], sa, 0, 0, 0);
                sa = __builtin_amdgcn_mfma_f32_16x16x32_f16(kf1, qf8[1], sa, 0, 0, 0);
                if (fullv) {
#pragma unroll
                    for (int j = 0; j < 4; ++j) st[t][j] = sa[j];
                } else {
#pragma unroll
                    for (int j = 0; j < 4; ++j) {
                        const int key = kt + t * 16 + lg * 4 + j;
                        st[t][j] = (key >= lo && key < hi) ? sa[j] : -1e30f;
                    }
                }
            }
            __builtin_amdgcn_s_setprio(0);

            // ---- half-hoist V fragments (t=0,1): cover LDS latency under softmax ----
            half4 vf01[2][4];
#pragma unroll
            for (int t = 0; t < 2; ++t)
#pragma unroll
                for (int dt = 0; dt < 4; ++dt)
                    vf01[t][dt] = *(const half4*)(Vb + vrb[t] + dt * 2048);

            // ---- per-lane max only (no cross-lane in common path) ----
            float lmax = fmaxf(fmaxf(st[0][0], st[0][1]), fmaxf(st[0][2], st[0][3]));
            lmax = fmaxf(lmax, fmaxf(fmaxf(st[1][0], st[1][1]), fmaxf(st[1][2], st[1][3])));
            lmax = fmaxf(lmax, fmaxf(fmaxf(st[2][0], st[2][1]), fmaxf(st[2][2], st[2][3])));
            lmax = fmaxf(lmax, fmaxf(fmaxf(st[3][0], st[3][1]), fmaxf(st[3][2], st[3][3])));

            // defer-max: shuffles + rescale only when some lane exceeds m+8*log2e
            if (__any(lmax > m_run + 11.54f)) {
                float tx = fmaxf(lmax, __shfl_xor(lmax, 16));
                tx = fmaxf(tx, __shfl_xor(tx, 32));
                const float mn = fmaxf(m_run, tx);
                const float a  = exp2f(m_run - mn);
#pragma unroll
                for (int dt = 0; dt < 4; ++dt)
#pragma unroll
                    for (int j = 0; j < 4; ++j) acc[dt][j] *= a;
#pragma unroll
                for (int j = 0; j < 4; ++j) acc_l[j] *= a;
                m_run = mn;
            }
            // all-masked rows self-heal at their first real tile (a=0 wipes accs)

            half4 pb[4];
#pragma unroll
            for (int t = 0; t < 4; ++t) {
                float e0 = exp2f(st[t][0] - m_run);
                float e1 = exp2f(st[t][1] - m_run);
                float e2 = exp2f(st[t][2] - m_run);
                float e3 = exp2f(st[t][3] - m_run);
                half2r a = __builtin_amdgcn_cvt_pkrtz(e0, e1);
                half2r b = __builtin_amdgcn_cvt_pkrtz(e2, e3);
                pb[t][0] = (_Float16)a[0]; pb[t][1] = (_Float16)a[1];
                pb[t][2] = (_Float16)b[0]; pb[t][3] = (_Float16)b[1];
            }

            // ---- PV + lsum: Ot += V^T P^T; acc_l += ones * P^T ----
            __builtin_amdgcn_s_setprio(1);
#pragma unroll
            for (int t = 0; t < 2; ++t) {
#pragma unroll
                for (int dt = 0; dt < 4; ++dt)
                    acc[dt] = __builtin_amdgcn_mfma_f32_16x16x16f16(vf01[t][dt], pb[t], acc[dt], 0, 0, 0);
                acc_l = __builtin_amdgcn_mfma_f32_16x16x16f16(onesv, pb[t], acc_l, 0, 0, 0);
            }
#pragma unroll
            for (int t = 2; t < 4; ++t) {
#pragma unroll
                for (int dt = 0; dt < 4; ++dt) {
                    half4 vf = *(const half4*)(Vb + vrb[t] + dt * 2048);
                    acc[dt] = __builtin_amdgcn_mfma_f32_16x16x16f16(vf, pb[t], acc[dt], 0, 0, 0);
                }
                acc_l = __builtin_amdgcn_mfma_f32_16x16x16f16(onesv, pb[t], acc_l, 0, 0, 0);
            }
            __builtin_amdgcn_s_setprio(0);
        }
        cur ^= 1;
    }

    const float inv = 1.0f / acc_l[0];   // all acc_l rows equal lsum[q=lr]
    float* orow = outg + ((size_t)h * TT + q) * DD;
#pragma unroll
    for (int dt = 0; dt < 4; ++dt) {
        float4v o;
#pragma unroll
        for (int j = 0; j < 4; ++j) o[j] = acc[dt][j] * inv;
        *(float4v*)(orow + dt * 16 + lg * 4) = o;
    }
#undef ISSUE
}

extern "C" void kernel_launch(void* const* d_in, const int* in_sizes, int n_in,
                              void* d_out, int out_size, void* d_ws, size_t ws_size,
                              hipStream_t stream) {
    const float* q  = (const float*)d_in[0];
    const float* k  = (const float*)d_in[1];
    const float* v  = (const float*)d_in[2];
    const int*   cu = (const int*)d_in[3];
    float* out = (float*)d_out;

    dim3 grid(HH * (TT / 64));   // 1024
    dim3 block(256);
    hipLaunchKernelGGL(pa_fwd, grid, block, 0, stream, q, k, v, cu, out);
}